// Round 1
// baseline (704.425 us; speedup 1.0000x reference)
//
#include <hip/hip_runtime.h>
#include <math.h>

#define NH   8
#define HW   32
#define LSEQ 2048
#define EMB  256
#define BB   2

#define FMA4(d, a, b2)                      \
  d.x = fmaf(a.x, b2.x, d.x);               \
  d.y = fmaf(a.y, b2.y, d.y);               \
  d.z = fmaf(a.z, b2.z, d.z);               \
  d.w = fmaf(a.w, b2.w, d.w);

// ---------------------------------------------------------------------------
// QKV projection: t[m,f] = sum_e X[m,e] * Wp[f,e], scatter into Q/K/V
// [b][h][l][32] with Q pre-scaled by hw^-0.5.  M=4096, N=768, K=256.
// Tile 64x64, 256 threads, 4x4 micro-tile.
// ---------------------------------------------------------------------------
__global__ __launch_bounds__(256) void qkv_gemm(
    const float* __restrict__ X, const float* __restrict__ Wp,
    float* __restrict__ Qw, float* __restrict__ Kw, float* __restrict__ Vw) {
  __shared__ __attribute__((aligned(16))) float As[16 * 68];
  __shared__ __attribute__((aligned(16))) float Bs[16 * 68];
  const int t = threadIdx.x;
  const int tn = t & 15, tm = t >> 4;
  const int m0 = blockIdx.y * 64, n0 = blockIdx.x * 64;
  const int lm = t >> 2, lc = t & 3;
  float acc[4][4] = {};
  for (int k0 = 0; k0 < 256; k0 += 16) {
    float4 av = *(const float4*)&X[(m0 + lm) * 256 + k0 + lc * 4];
    float4 bv = *(const float4*)&Wp[(n0 + lm) * 256 + k0 + lc * 4];
    __syncthreads();
    As[(lc * 4 + 0) * 68 + lm] = av.x; As[(lc * 4 + 1) * 68 + lm] = av.y;
    As[(lc * 4 + 2) * 68 + lm] = av.z; As[(lc * 4 + 3) * 68 + lm] = av.w;
    Bs[(lc * 4 + 0) * 68 + lm] = bv.x; Bs[(lc * 4 + 1) * 68 + lm] = bv.y;
    Bs[(lc * 4 + 2) * 68 + lm] = bv.z; Bs[(lc * 4 + 3) * 68 + lm] = bv.w;
    __syncthreads();
#pragma unroll
    for (int kk = 0; kk < 16; ++kk) {
      float4 a4 = *(const float4*)&As[kk * 68 + tm * 4];
      float4 b4 = *(const float4*)&Bs[kk * 68 + tn * 4];
      float ar[4] = {a4.x, a4.y, a4.z, a4.w};
      float br[4] = {b4.x, b4.y, b4.z, b4.w};
#pragma unroll
      for (int i = 0; i < 4; ++i)
#pragma unroll
        for (int j = 0; j < 4; ++j) acc[i][j] = fmaf(ar[i], br[j], acc[i][j]);
    }
  }
  const float qscale = 0.17677669529663687f;  // 32^-0.5
#pragma unroll
  for (int i = 0; i < 4; ++i) {
    int m = m0 + tm * 4 + i;
    int bb = m >> 11, l = m & 2047;
#pragma unroll
    for (int j = 0; j < 4; ++j) {
      int f = n0 + tn * 4 + j;
      int h = f / 96, r = f - h * 96;
      int base = ((bb * NH + h) * LSEQ + l) * HW;
      float v = acc[i][j];
      if (r < 32)       Qw[base + r]      = v * qscale;
      else if (r < 64)  Kw[base + r - 32] = v;
      else              Vw[base + r - 64] = v;
    }
  }
}

// ---------------------------------------------------------------------------
// Flash attention with pair bias.  One block = (b, 16 q-rows, ALL 8 heads)
// so the [b][q][k][h] bias reads are fully contiguous.  k-tile = 16.
// Thread t: h = t>>5, tq = (t>>3)&3 (4 q's), tg = t&7 (k-group for S,
// c-group for PV).  Softmax m/l/alpha live redundantly in the 8-lane
// shuffle group (same lanes do S and PV) -> no LDS softmax state.
// ---------------------------------------------------------------------------
__global__ __launch_bounds__(256) void attn(
    const float* __restrict__ Qg, const float* __restrict__ Kg,
    const float* __restrict__ Vg, const float* __restrict__ Bias,
    float* __restrict__ Y) {
  __shared__ __attribute__((aligned(16))) float Qs[8 * 16 * 36];  // [h][q][c] pad36
  __shared__ __attribute__((aligned(16))) float Ks[8 * 16 * 36];  // [h][k][c] pad36
  __shared__ __attribute__((aligned(16))) float Vs[8 * 16 * 32];  // [h][k][c]
  __shared__ __attribute__((aligned(16))) float SbPt[2560];       // bias [q][k][h+pad] / Pt [h][k][q+pad]
  const int t = threadIdx.x;
  const int b = blockIdx.y;
  const int q0g = blockIdx.x * 16;
  const int h = t >> 5;
  const int tq = (t >> 3) & 3;
  const int tg = t & 7;
  const int q0 = tq * 4;

  // stage Q tile once: 8h x 16q x 32c
#pragma unroll
  for (int j = 0; j < 4; ++j) {
    int fi = t + j * 256;
    int hh = fi >> 7, rem = fi & 127;
    int qq = rem >> 3, c4 = rem & 7;
    float4 v = *(const float4*)&Qg[((b * NH + hh) * LSEQ + q0g + qq) * HW + c4 * 4];
    *(float4*)&Qs[(hh * 16 + qq) * 36 + c4 * 4] = v;
  }

  float m_i[4], l_i[4], o[4][4];
#pragma unroll
  for (int i = 0; i < 4; ++i) {
    m_i[i] = -1e30f; l_i[i] = 0.f;
#pragma unroll
    for (int j = 0; j < 4; ++j) o[i][j] = 0.f;
  }

  for (int kb = 0; kb < LSEQ; kb += 16) {
    __syncthreads();  // previous-iter reads of Ks/Vs/Pt done (also covers Qs staging)
    // stage K,V tile: 8h x 16k x 32c each
#pragma unroll
    for (int j = 0; j < 4; ++j) {
      int fi = t + j * 256;
      int hh = fi >> 7, rem = fi & 127;
      int kk = rem >> 3, c4 = rem & 7;
      float4 kv = *(const float4*)&Kg[((b * NH + hh) * LSEQ + kb + kk) * HW + c4 * 4];
      *(float4*)&Ks[(hh * 16 + kk) * 36 + c4 * 4] = kv;
      float4 vv = *(const float4*)&Vg[((b * NH + hh) * LSEQ + kb + kk) * HW + c4 * 4];
      *(float4*)&Vs[(hh * 16 + kk) * 32 + c4 * 4] = vv;
    }
    // stage bias tile coalesced: [q][k][h] with h-dim padded to 9
#pragma unroll
    for (int j = 0; j < 8; ++j) {
      int idx = t + j * 256;
      int qq = idx >> 7, kh = idx & 127;
      SbPt[qq * 144 + (kh >> 3) * 9 + (kh & 7)] =
          Bias[((b * LSEQ + q0g + qq) * LSEQ + kb) * 8 + kh];
    }
    __syncthreads();

    // S = Q K^T (+bias): thread computes 4q x 2k, contraction over c as 4-wide partials
    float4 acc[4][2];
#pragma unroll
    for (int i = 0; i < 4; ++i)
#pragma unroll
      for (int j = 0; j < 2; ++j) acc[i][j] = make_float4(0.f, 0.f, 0.f, 0.f);
#pragma unroll
    for (int c4 = 0; c4 < 8; ++c4) {
      float4 k0v = *(const float4*)&Ks[(h * 16 + tg * 2 + 0) * 36 + c4 * 4];
      float4 k1v = *(const float4*)&Ks[(h * 16 + tg * 2 + 1) * 36 + c4 * 4];
#pragma unroll
      for (int i = 0; i < 4; ++i) {
        float4 qv = *(const float4*)&Qs[(h * 16 + q0 + i) * 36 + c4 * 4];
        FMA4(acc[i][0], qv, k0v);
        FMA4(acc[i][1], qv, k1v);
      }
    }
    float s[4][2];
#pragma unroll
    for (int i = 0; i < 4; ++i)
#pragma unroll
      for (int j = 0; j < 2; ++j) {
        float4 a = acc[i][j];
        s[i][j] = (a.x + a.y) + (a.z + a.w) +
                  SbPt[(q0 + i) * 144 + (tg * 2 + j) * 9 + h];
      }

    // online softmax over this 16-k tile (row = (q,h), spread across 8 tg lanes)
    float alpha[4];
#pragma unroll
    for (int i = 0; i < 4; ++i) {
      float mx = fmaxf(s[i][0], s[i][1]);
      mx = fmaxf(mx, __shfl_xor(mx, 1, 64));
      mx = fmaxf(mx, __shfl_xor(mx, 2, 64));
      mx = fmaxf(mx, __shfl_xor(mx, 4, 64));
      float mnew = fmaxf(m_i[i], mx);
      float p0 = __expf(s[i][0] - mnew);
      float p1 = __expf(s[i][1] - mnew);
      float ps = p0 + p1;
      ps += __shfl_xor(ps, 1, 64);
      ps += __shfl_xor(ps, 2, 64);
      ps += __shfl_xor(ps, 4, 64);
      alpha[i] = __expf(m_i[i] - mnew);
      l_i[i] = l_i[i] * alpha[i] + ps;
      m_i[i] = mnew;
      s[i][0] = p0; s[i][1] = p1;
    }
    __syncthreads();  // all bias reads done before Pt overwrites the buffer
    // write P transposed: Pt[h][k][q] (row pad 20), float4 over the thread's 4 q's
#pragma unroll
    for (int j = 0; j < 2; ++j) {
      float4 pv = make_float4(s[0][j], s[1][j], s[2][j], s[3][j]);
      *(float4*)&SbPt[(h * 16 + tg * 2 + j) * 20 + q0] = pv;
    }
    __syncthreads();

    // O update: thread covers 4q x 4c (c-group = tg)
#pragma unroll
    for (int i = 0; i < 4; ++i)
#pragma unroll
      for (int j = 0; j < 4; ++j) o[i][j] *= alpha[i];
#pragma unroll
    for (int kk = 0; kk < 16; ++kk) {
      float4 pv = *(const float4*)&SbPt[(h * 16 + kk) * 20 + q0];
      float4 vv = *(const float4*)&Vs[(h * 16 + kk) * 32 + tg * 4];
      float pa[4] = {pv.x, pv.y, pv.z, pv.w};
      float va[4] = {vv.x, vv.y, vv.z, vv.w};
#pragma unroll
      for (int i = 0; i < 4; ++i)
#pragma unroll
        for (int j = 0; j < 4; ++j) o[i][j] = fmaf(pa[i], va[j], o[i][j]);
    }
  }

  // epilogue: y[b][q][h*32+c] = o / l
#pragma unroll
  for (int i = 0; i < 4; ++i) {
    float inv = 1.0f / l_i[i];
    float4 r = make_float4(o[i][0] * inv, o[i][1] * inv, o[i][2] * inv, o[i][3] * inv);
    *(float4*)&Y[(b * LSEQ + q0g + q0 + i) * EMB + h * HW + tg * 4] = r;
  }
}

// ---------------------------------------------------------------------------
// Output projection: Out[m,n] = sum_e Y[m,e] * Wo[n,e] + bo[n].
// M=4096, N=256, K=256.  Same tiling as qkv_gemm.
// ---------------------------------------------------------------------------
__global__ __launch_bounds__(256) void out_gemm(
    const float* __restrict__ Yg, const float* __restrict__ Wo,
    const float* __restrict__ bo, float* __restrict__ Out) {
  __shared__ __attribute__((aligned(16))) float As[16 * 68];
  __shared__ __attribute__((aligned(16))) float Bs[16 * 68];
  const int t = threadIdx.x;
  const int tn = t & 15, tm = t >> 4;
  const int m0 = blockIdx.y * 64, n0 = blockIdx.x * 64;
  const int lm = t >> 2, lc = t & 3;
  float acc[4][4] = {};
  for (int k0 = 0; k0 < 256; k0 += 16) {
    float4 av = *(const float4*)&Yg[(m0 + lm) * 256 + k0 + lc * 4];
    float4 bv = *(const float4*)&Wo[(n0 + lm) * 256 + k0 + lc * 4];
    __syncthreads();
    As[(lc * 4 + 0) * 68 + lm] = av.x; As[(lc * 4 + 1) * 68 + lm] = av.y;
    As[(lc * 4 + 2) * 68 + lm] = av.z; As[(lc * 4 + 3) * 68 + lm] = av.w;
    Bs[(lc * 4 + 0) * 68 + lm] = bv.x; Bs[(lc * 4 + 1) * 68 + lm] = bv.y;
    Bs[(lc * 4 + 2) * 68 + lm] = bv.z; Bs[(lc * 4 + 3) * 68 + lm] = bv.w;
    __syncthreads();
#pragma unroll
    for (int kk = 0; kk < 16; ++kk) {
      float4 a4 = *(const float4*)&As[kk * 68 + tm * 4];
      float4 b4 = *(const float4*)&Bs[kk * 68 + tn * 4];
      float ar[4] = {a4.x, a4.y, a4.z, a4.w};
      float br[4] = {b4.x, b4.y, b4.z, b4.w};
#pragma unroll
      for (int i = 0; i < 4; ++i)
#pragma unroll
        for (int j = 0; j < 4; ++j) acc[i][j] = fmaf(ar[i], br[j], acc[i][j]);
    }
  }
#pragma unroll
  for (int i = 0; i < 4; ++i) {
    int m = m0 + tm * 4 + i;
#pragma unroll
    for (int j = 0; j < 4; ++j) {
      int n = n0 + tn * 4 + j;
      Out[m * 256 + n] = acc[i][j] + bo[n];
    }
  }
}

extern "C" void kernel_launch(void* const* d_in, const int* in_sizes, int n_in,
                              void* d_out, int out_size, void* d_ws, size_t ws_size,
                              hipStream_t stream) {
  const float* X    = (const float*)d_in[0];
  const float* Bias = (const float*)d_in[1];
  const float* Wp   = (const float*)d_in[2];
  const float* Wo   = (const float*)d_in[3];
  const float* bo   = (const float*)d_in[4];
  float* Out = (float*)d_out;

  const size_t qkv_elems = (size_t)BB * NH * LSEQ * HW;  // 1,048,576
  float* Qw = (float*)d_ws;
  float* Kw = Qw + qkv_elems;
  float* Vw = Kw + qkv_elems;
  float* Yw = Vw + qkv_elems;  // 4096 x 256

  qkv_gemm<<<dim3(12, 64), 256, 0, stream>>>(X, Wp, Qw, Kw, Vw);
  attn<<<dim3(LSEQ / 16, BB), 256, 0, stream>>>(Qw, Kw, Vw, Bias, Yw);
  out_gemm<<<dim3(4, 64), 256, 0, stream>>>(Yw, Wo, bo, Out);
}